// Round 1
// baseline (2311.603 us; speedup 1.0000x reference)
//
#include <hip/hip_runtime.h>
#include <hip/hip_bf16.h>

#define NSP   20000
#define NSPAT 10000
#define ESS   160000
#define EBIP  320000
#define ESP   320000

static inline int cdiv_host(long a, long b) { return (int)((a + b - 1) / b); }

__device__ __forceinline__ float wave_red_sum(float p) {
#pragma unroll
  for (int m = 32; m >= 1; m >>= 1) p += __shfl_xor(p, m, 64);
  return p;
}

// ---------------------------------------------------------------------------
// mask format detector: 0 = int32 {0,1}, 1 = bytes {0,1}, 2 = float32 {0,1.0f}
// ---------------------------------------------------------------------------
__global__ void detect_mask_kernel(const unsigned int* __restrict__ m, int* __restrict__ flag) {
  if (threadIdx.x == 0 && blockIdx.x == 0) {
    int allint = 1, allfloat = 1;
    for (int i = 0; i < 256; ++i) {
      unsigned int w = m[i];
      if (w != 0u && w != 1u) allint = 0;
      if (w != 0u && w != 0x3f800000u) allfloat = 0;
    }
    *flag = allint ? 0 : (allfloat ? 2 : 1);
  }
}

// ---------------------------------------------------------------------------
// species input concat: [mean(32) | std(32) | vis(32) | gen(64) | phylo(128)]
// ---------------------------------------------------------------------------
__global__ void build_spcat_kernel(const float* __restrict__ mean, const float* __restrict__ stdv,
                                   const void* __restrict__ mask, const int* __restrict__ flag,
                                   const float* __restrict__ gen, const float* __restrict__ phy,
                                   float* __restrict__ out) {
  const long total = (long)NSP * 288;
  int mode = *flag;
  for (long i = (long)blockIdx.x * blockDim.x + threadIdx.x; i < total;
       i += (long)gridDim.x * blockDim.x) {
    int n = (int)(i / 288), c = (int)(i % 288);
    float v;
    if (c < 32) v = mean[(long)n * 32 + c];
    else if (c < 64) v = stdv[(long)n * 32 + (c - 32)];
    else if (c < 96) {
      long j = (long)n * 32 + (c - 64);
      int mv;
      if (mode == 0) mv = ((const int*)mask)[j];
      else if (mode == 2) mv = (((const float*)mask)[j] != 0.0f);
      else mv = (int)((const unsigned char*)mask)[j];
      v = mv ? 0.f : 1.f;   // vis = ~mask
    } else if (c < 160) v = gen[(long)n * 64 + (c - 96)];
    else v = phy[(long)n * 128 + (c - 160)];
    out[i] = v;
  }
}

__global__ void concat2_kernel(const float* __restrict__ A, int wa,
                               const float* __restrict__ B, int wb,
                               int M, float* __restrict__ out) {
  const int wt = wa + wb;
  const long total = (long)M * wt;
  for (long i = (long)blockIdx.x * blockDim.x + threadIdx.x; i < total;
       i += (long)gridDim.x * blockDim.x) {
    int m = (int)(i / wt), c = (int)(i % wt);
    out[i] = (c < wa) ? A[(long)m * wa + c] : B[(long)m * wb + (c - wa)];
  }
}

// ---------------------------------------------------------------------------
// CSR build
// ---------------------------------------------------------------------------
__global__ void count_kernel(const int* __restrict__ col, int E, int* __restrict__ cnt) {
  for (int i = blockIdx.x * blockDim.x + threadIdx.x; i < E; i += gridDim.x * blockDim.x)
    atomicAdd(&cnt[col[i]], 1);
}

__global__ __launch_bounds__(1024) void scan_kernel(const int* __restrict__ cnt, int n,
                                                    int* __restrict__ ptr) {
  __shared__ int part[1024];
  int t = threadIdx.x;
  int ch = (n + 1023) / 1024;
  int beg = t * ch, end = min(beg + ch, n);
  int s = 0;
  for (int i = beg; i < end; ++i) s += cnt[i];
  part[t] = s;
  __syncthreads();
  for (int off = 1; off < 1024; off <<= 1) {
    int v = (t >= off) ? part[t - off] : 0;
    __syncthreads();
    part[t] += v;
    __syncthreads();
  }
  int run = (t == 0) ? 0 : part[t - 1];
  for (int i = beg; i < end; ++i) { ptr[i] = run; run += cnt[i]; }
  if (t == 1023) ptr[n] = part[1023];
}

__global__ void fill_kernel(const int* __restrict__ row, const int* __restrict__ col,
                            const float* __restrict__ ea, int E,
                            const int* __restrict__ ptr, int* __restrict__ cur,
                            int* __restrict__ csrc, float* __restrict__ cea) {
  for (int i = blockIdx.x * blockDim.x + threadIdx.x; i < E; i += gridDim.x * blockDim.x) {
    int d = col[i];
    int pos = ptr[d] + atomicAdd(&cur[d], 1);
    csrc[pos] = row[i];
    cea[pos] = ea[i];
  }
}

__global__ void easum_kernel(const int* __restrict__ col, const float* __restrict__ ea, int E,
                             float* __restrict__ s) {
  for (int i = blockIdx.x * blockDim.x + threadIdx.x; i < E; i += gridDim.x * blockDim.x)
    atomicAdd(&s[col[i]], ea[i]);
}

__global__ void leafin_kernel(const float* __restrict__ s, const int* __restrict__ cnt, int N,
                              float* __restrict__ lea) {
  for (int i = blockIdx.x * blockDim.x + threadIdx.x; i < N; i += gridDim.x * blockDim.x)
    lea[i] = s[i] / (float)max(cnt[i], 1);
}

// dot_e[h] = sum_c We[h*64+c] * a_e[h*64+c]   (launch H*64 threads)
__global__ void dote_kernel(const float* __restrict__ We, const float* __restrict__ ae,
                            float* __restrict__ dote) {
  int t = threadIdx.x;
  float p = wave_red_sum(We[t] * ae[t]);
  if ((t & 63) == 0) dote[t >> 6] = p;
}

// ---------------------------------------------------------------------------
// Projection: Y[M,NOUT] = X[M,K] @ W[K,NOUT]  (+bias, +relu), optional per-head
// attention dots al_s/al_d (head = col/64).  W staged in 64KB LDS chunks.
// ---------------------------------------------------------------------------
template <int NOUT>
__global__ __launch_bounds__(256) void proj_kernel(
    const float* __restrict__ X, int M, int K,
    const float* __restrict__ W, const float* __restrict__ bias, int relu,
    const float* __restrict__ a_s, const float* __restrict__ a_d,
    float* __restrict__ al_s, float* __restrict__ al_d,
    float* __restrict__ Y) {
  const int G = 256 / NOUT;          // row groups per block
  const int RPT = 8;                 // rows per thread
  const int KC = (NOUT == 256) ? 64 : 256;
  const int H = NOUT / 64;
  __shared__ float wl[16384];        // 64 KB
  int t = threadIdx.x;
  int col = t % NOUT;
  int rg = t / NOUT;
  long row0 = (long)blockIdx.x * (G * RPT) + (long)rg * RPT;
  float acc[RPT];
#pragma unroll
  for (int r = 0; r < RPT; ++r) acc[r] = 0.f;

  for (int k0 = 0; k0 < K; k0 += KC) {
    int kc = min(KC, K - k0);
    __syncthreads();
    for (int i = t; i < kc * NOUT; i += 256) wl[i] = W[(long)k0 * NOUT + i];
    __syncthreads();
    long rem = (long)M - row0;
    int rmax = rem > RPT ? RPT : (rem > 0 ? (int)rem : 0);
    for (int r = 0; r < rmax; ++r) {
      const float* xr = X + (row0 + r) * K + k0;
      float a = acc[r];
      for (int k = 0; k < kc; ++k) a = fmaf(xr[k], wl[k * NOUT + col], a);
      acc[r] = a;
    }
  }

  float as_c = a_s ? a_s[col] : 0.f;
  float ad_c = a_d ? a_d[col] : 0.f;
  long rem = (long)M - row0;
  int rmax = rem > RPT ? RPT : (rem > 0 ? (int)rem : 0);
  for (int r = 0; r < rmax; ++r) {
    long m = row0 + r;
    float v = acc[r];
    if (bias) v += bias[col];
    if (relu) v = fmaxf(v, 0.f);
    Y[m * NOUT + col] = v;
    if (a_s) {
      float p = wave_red_sum(acc[r] * as_c);
      if ((col & 63) == 0) al_s[m * H + (col >> 6)] = p;
    }
    if (a_d) {
      float p = wave_red_sum(acc[r] * ad_c);
      if ((col & 63) == 0) al_d[m * H + (col >> 6)] = p;
    }
  }
}

// ---------------------------------------------------------------------------
// GAT aggregation: one block per dst node; wave = head, lane = channel.
// Online softmax over incoming edges (+ optional virtual self loop).
// Epilogue: mean over heads (or H=1 passthrough) + bias + relu.
// ---------------------------------------------------------------------------
template <int H, bool SELFLOOP, bool MEANHEADS>
__global__ __launch_bounds__(H * 64) void gat_agg(
    int Nd, const int* __restrict__ dptr, const int* __restrict__ csr_src,
    const float* __restrict__ csr_ea, const float* __restrict__ al_s,
    const float* __restrict__ al_d, const float* __restrict__ dote,
    const float* __restrict__ loop_ea, const float* __restrict__ hs,
    const float* __restrict__ bias, float* __restrict__ out) {
  int n = blockIdx.x;
  if (n >= Nd) return;
  int t = threadIdx.x;
  int h = t >> 6, c = t & 63;
  float m = -INFINITY, den = 0.f, acc = 0.f;
  float ald = al_d[(long)n * H + h];
  float de = dote[h];
  int e0 = dptr[n], e1 = dptr[n + 1];
  for (int e = e0; e < e1; ++e) {
    int src = csr_src[e];
    float l = al_s[(long)src * H + h] + ald + csr_ea[e] * de;
    l = (l > 0.f) ? l : 0.2f * l;
    float hv = hs[(long)src * (H * 64) + (h << 6) + c];
    if (l > m) { float s = expf(m - l); den *= s; acc *= s; m = l; }
    float ex = expf(l - m);
    den += ex;
    acc += ex * hv;
  }
  if (SELFLOOP) {
    float l = al_s[(long)n * H + h] + ald + loop_ea[n] * de;
    l = (l > 0.f) ? l : 0.2f * l;
    float hv = hs[(long)n * (H * 64) + (h << 6) + c];
    if (l > m) { float s = expf(m - l); den *= s; acc *= s; m = l; }
    float ex = expf(l - m);
    den += ex;
    acc += ex * hv;
  }
  float o = acc / (den + 1e-16f);
  if constexpr (MEANHEADS) {
    __shared__ float red[H][64];
    red[h][c] = o;
    __syncthreads();
    if (t < 64) {
      float s = 0.f;
#pragma unroll
      for (int hh = 0; hh < H; ++hh) s += red[hh][t];
      s = s * (1.f / H) + bias[t];
      out[(long)n * 64 + t] = fmaxf(s, 0.f);
    }
  } else {
    out[(long)n * 64 + t] = fmaxf(o + bias[t], 0.f);
  }
}

// ---------------------------------------------------------------------------
// final: mean = ms[:, :32]; std = softplus(ms[:, 32:]) + 1e-6
// ---------------------------------------------------------------------------
__global__ void final_kernel(const float* __restrict__ ms, float* __restrict__ out) {
  const long total = (long)NSP * 32;
  for (long i = (long)blockIdx.x * blockDim.x + threadIdx.x; i < total;
       i += (long)gridDim.x * blockDim.x) {
    long n = i >> 5;
    int c = (int)(i & 31);
    out[i] = ms[n * 64 + c];
    float x = ms[n * 64 + 32 + c];
    float sp = fmaxf(x, 0.f) + log1pf(expf(-fabsf(x)));
    out[total + i] = sp + 1e-6f;
  }
}

// ---------------------------------------------------------------------------
extern "C" void kernel_launch(void* const* d_in, const int* in_sizes, int n_in,
                              void* d_out, int out_size, void* d_ws, size_t ws_size,
                              hipStream_t stream) {
  const float* sp_mean = (const float*)d_in[0];
  const float* sp_std  = (const float*)d_in[1];
  const void*  nanmask = d_in[2];
  const float* sp_gen  = (const float*)d_in[3];
  const float* sp_phy  = (const float*)d_in[4];
  const float* spat_x  = (const float*)d_in[5];
  const float* spat_g  = (const float*)d_in[6];
  const int*   ss_ei   = (const int*)d_in[7];
  const float* ss_ea   = (const float*)d_in[8];
  const int*   bip_ei  = (const int*)d_in[9];
  const float* bip_ea  = (const float*)d_in[10];
  const int*   sp_ei   = (const int*)d_in[11];
  const float* sp_ea   = (const float*)d_in[12];
  const float* sg0_W = (const float*)d_in[13]; const float* sg0_as = (const float*)d_in[14];
  const float* sg0_ad = (const float*)d_in[15]; const float* sg0_ae = (const float*)d_in[16];
  const float* sg0_We = (const float*)d_in[17]; const float* sg0_b = (const float*)d_in[18];
  const float* sg1_W = (const float*)d_in[19]; const float* sg1_as = (const float*)d_in[20];
  const float* sg1_ad = (const float*)d_in[21]; const float* sg1_ae = (const float*)d_in[22];
  const float* sg1_We = (const float*)d_in[23]; const float* sg1_b = (const float*)d_in[24];
  const float* pg0_W = (const float*)d_in[25]; const float* pg0_as = (const float*)d_in[26];
  const float* pg0_ad = (const float*)d_in[27]; const float* pg0_ae = (const float*)d_in[28];
  const float* pg0_We = (const float*)d_in[29]; const float* pg0_b = (const float*)d_in[30];
  const float* pg1_W = (const float*)d_in[31]; const float* pg1_as = (const float*)d_in[32];
  const float* pg1_ad = (const float*)d_in[33]; const float* pg1_ae = (const float*)d_in[34];
  const float* pg1_We = (const float*)d_in[35]; const float* pg1_b = (const float*)d_in[36];
  const float* bp_Ws = (const float*)d_in[37]; const float* bp_Wd = (const float*)d_in[38];
  const float* bp_as = (const float*)d_in[39]; const float* bp_ad = (const float*)d_in[40];
  const float* bp_ae = (const float*)d_in[41]; const float* bp_We = (const float*)d_in[42];
  const float* bp_b  = (const float*)d_in[43];
  const float* sl_W  = (const float*)d_in[44]; const float* sl_b  = (const float*)d_in[45];
  const float* fc_W  = (const float*)d_in[46]; const float* fc_b  = (const float*)d_in[47];

  // ---- workspace layout ----
  char* wsb = (char*)d_ws;
  size_t off = 0;
  auto A = [&](size_t nbytes) -> void* {
    void* p = wsb + off;
    off += (nbytes + 255) & ~(size_t)255;
    return p;
  };
  int*   flag  = (int*)A(4);
  float* dotes = (float*)A(5 * 4 * sizeof(float));     // 5 layers x 4 heads
  float* alS   = (float*)A((size_t)NSP * 4 * 4);       // [<=20000, H<=4]
  float* alD   = (float*)A((size_t)NSP * 4 * 4);
  float* R1    = (float*)A((size_t)NSP * 288 * 4);     // sp_cat / part / x_sp
  float* sp_in = (float*)A((size_t)NSP * 64 * 4);
  float* h0    = (float*)A((size_t)NSPAT * 16 * 4);
  float* h_a   = (float*)A((size_t)NSPAT * 64 * 4);
  float* h_b   = (float*)A((size_t)NSPAT * 64 * 4);
  float* HS    = (float*)A((size_t)NSP * 256 * 4);     // projection scratch
  float* sts   = (float*)A((size_t)NSP * 64 * 4);      // bip out, later x2
  float* x1    = (float*)A((size_t)NSP * 64 * 4);      // pg0 out, later ms
  int*   ss_ptr = (int*)A((NSPAT + 1) * 4);
  int*   ss_cnt = (int*)A((NSPAT + 1) * 4);
  int*   ss_cur = (int*)A((NSPAT + 1) * 4);
  int*   ss_src = (int*)A((size_t)ESS * 4);
  float* ss_cea = (float*)A((size_t)ESS * 4);
  float* ss_sum = (float*)A((size_t)NSPAT * 4);
  float* ss_lea = (float*)A((size_t)NSPAT * 4);
  int*   bp_ptr = (int*)A((NSP + 1) * 4);
  int*   bp_cnt = (int*)A((NSP + 1) * 4);
  int*   bp_cur = (int*)A((NSP + 1) * 4);
  int*   bp_src = (int*)A((size_t)EBIP * 4);
  float* bp_cea = (float*)A((size_t)EBIP * 4);
  int*   pp_ptr = (int*)A((NSP + 1) * 4);
  int*   pp_cnt = (int*)A((NSP + 1) * 4);
  int*   pp_cur = (int*)A((NSP + 1) * 4);
  int*   pp_src = (int*)A((size_t)ESP * 4);
  float* pp_cea = (float*)A((size_t)ESP * 4);
  float* pp_sum = (float*)A((size_t)NSP * 4);
  float* pp_lea = (float*)A((size_t)NSP * 4);
  (void)ws_size; (void)in_sizes; (void)n_in; (void)out_size;

  const int TB = 256;
  // ---- zero counters ----
  hipMemsetAsync(ss_cnt, 0, (NSPAT + 1) * 4, stream);
  hipMemsetAsync(ss_cur, 0, (NSPAT + 1) * 4, stream);
  hipMemsetAsync(ss_sum, 0, NSPAT * 4, stream);
  hipMemsetAsync(bp_cnt, 0, (NSP + 1) * 4, stream);
  hipMemsetAsync(bp_cur, 0, (NSP + 1) * 4, stream);
  hipMemsetAsync(pp_cnt, 0, (NSP + 1) * 4, stream);
  hipMemsetAsync(pp_cur, 0, (NSP + 1) * 4, stream);
  hipMemsetAsync(pp_sum, 0, NSP * 4, stream);

  // ---- graph builds ----
  count_kernel<<<cdiv_host(ESS, TB), TB, 0, stream>>>(ss_ei + ESS, ESS, ss_cnt);
  scan_kernel<<<1, 1024, 0, stream>>>(ss_cnt, NSPAT, ss_ptr);
  fill_kernel<<<cdiv_host(ESS, TB), TB, 0, stream>>>(ss_ei, ss_ei + ESS, ss_ea, ESS, ss_ptr, ss_cur, ss_src, ss_cea);
  easum_kernel<<<cdiv_host(ESS, TB), TB, 0, stream>>>(ss_ei + ESS, ss_ea, ESS, ss_sum);
  leafin_kernel<<<cdiv_host(NSPAT, TB), TB, 0, stream>>>(ss_sum, ss_cnt, NSPAT, ss_lea);

  count_kernel<<<cdiv_host(EBIP, TB), TB, 0, stream>>>(bip_ei + EBIP, EBIP, bp_cnt);
  scan_kernel<<<1, 1024, 0, stream>>>(bp_cnt, NSP, bp_ptr);
  fill_kernel<<<cdiv_host(EBIP, TB), TB, 0, stream>>>(bip_ei, bip_ei + EBIP, bip_ea, EBIP, bp_ptr, bp_cur, bp_src, bp_cea);

  count_kernel<<<cdiv_host(ESP, TB), TB, 0, stream>>>(sp_ei + ESP, ESP, pp_cnt);
  scan_kernel<<<1, 1024, 0, stream>>>(pp_cnt, NSP, pp_ptr);
  fill_kernel<<<cdiv_host(ESP, TB), TB, 0, stream>>>(sp_ei, sp_ei + ESP, sp_ea, ESP, pp_ptr, pp_cur, pp_src, pp_cea);
  easum_kernel<<<cdiv_host(ESP, TB), TB, 0, stream>>>(sp_ei + ESP, sp_ea, ESP, pp_sum);
  leafin_kernel<<<cdiv_host(NSP, TB), TB, 0, stream>>>(pp_sum, pp_cnt, NSP, pp_lea);

  // ---- species input MLP ----
  detect_mask_kernel<<<1, 64, 0, stream>>>((const unsigned int*)nanmask, flag);
  build_spcat_kernel<<<cdiv_host((long)NSP * 288, TB), TB, 0, stream>>>(sp_mean, sp_std, nanmask, flag, sp_gen, sp_phy, R1);
  proj_kernel<64><<<cdiv_host(NSP, 32), TB, 0, stream>>>(R1, NSP, 288, sl_W, sl_b, 1,
      nullptr, nullptr, nullptr, nullptr, sp_in);

  // ---- spatial GNN ----
  concat2_kernel<<<cdiv_host((long)NSPAT * 16, TB), TB, 0, stream>>>(spat_x, 12, spat_g, 4, NSPAT, h0);
  dote_kernel<<<1, 256, 0, stream>>>(sg0_We, sg0_ae, dotes + 0);
  proj_kernel<256><<<cdiv_host(NSPAT, 8), TB, 0, stream>>>(h0, NSPAT, 16, sg0_W, nullptr, 0,
      sg0_as, sg0_ad, alS, alD, HS);
  gat_agg<4, true, true><<<NSPAT, 256, 0, stream>>>(NSPAT, ss_ptr, ss_src, ss_cea, alS, alD,
      dotes + 0, ss_lea, HS, sg0_b, h_a);
  dote_kernel<<<1, 256, 0, stream>>>(sg1_We, sg1_ae, dotes + 4);
  proj_kernel<256><<<cdiv_host(NSPAT, 8), TB, 0, stream>>>(h_a, NSPAT, 64, sg1_W, nullptr, 0,
      sg1_as, sg1_ad, alS, alD, HS);
  gat_agg<4, true, true><<<NSPAT, 256, 0, stream>>>(NSPAT, ss_ptr, ss_src, ss_cea, alS, alD,
      dotes + 4, ss_lea, HS, sg1_b, h_b);

  // ---- bipartite GAT (spatial -> species), H=1, concat ----
  dote_kernel<<<1, 64, 0, stream>>>(bp_We, bp_ae, dotes + 8);
  proj_kernel<64><<<cdiv_host(NSPAT, 32), TB, 0, stream>>>(h_b, NSPAT, 64, bp_Ws, nullptr, 0,
      bp_as, nullptr, alS, nullptr, h_a);   // h_a := hs_src [NSPAT,64]
  concat2_kernel<<<cdiv_host((long)NSP * 192, TB), TB, 0, stream>>>(sp_gen, 64, sp_phy, 128, NSP, R1);
  proj_kernel<64><<<cdiv_host(NSP, 32), TB, 0, stream>>>(R1, NSP, 192, bp_Wd, nullptr, 0,
      nullptr, bp_ad, nullptr, alD, HS);    // HS := hd (only al_d used)
  gat_agg<1, false, false><<<NSP, 64, 0, stream>>>(NSP, bp_ptr, bp_src, bp_cea, alS, alD,
      dotes + 8, nullptr, h_a, bp_b, sts);

  // ---- species GNN ----
  concat2_kernel<<<cdiv_host((long)NSP * 128, TB), TB, 0, stream>>>(sts, 64, sp_in, 64, NSP, R1);
  dote_kernel<<<1, 256, 0, stream>>>(pg0_We, pg0_ae, dotes + 12);
  proj_kernel<256><<<cdiv_host(NSP, 8), TB, 0, stream>>>(R1, NSP, 128, pg0_W, nullptr, 0,
      pg0_as, pg0_ad, alS, alD, HS);
  gat_agg<4, true, true><<<NSP, 256, 0, stream>>>(NSP, pp_ptr, pp_src, pp_cea, alS, alD,
      dotes + 12, pp_lea, HS, pg0_b, x1);
  dote_kernel<<<1, 256, 0, stream>>>(pg1_We, pg1_ae, dotes + 16);
  proj_kernel<256><<<cdiv_host(NSP, 8), TB, 0, stream>>>(x1, NSP, 64, pg1_W, nullptr, 0,
      pg1_as, pg1_ad, alS, alD, HS);
  gat_agg<4, true, true><<<NSP, 256, 0, stream>>>(NSP, pp_ptr, pp_src, pp_cea, alS, alD,
      dotes + 16, pp_lea, HS, pg1_b, sts);  // sts := x2

  // ---- final linear + split ----
  proj_kernel<64><<<cdiv_host(NSP, 32), TB, 0, stream>>>(sts, NSP, 64, fc_W, fc_b, 0,
      nullptr, nullptr, nullptr, nullptr, x1);  // x1 := ms
  final_kernel<<<cdiv_host((long)NSP * 32, TB), TB, 0, stream>>>(x1, (float*)d_out);
}

// Round 2
// 1033.933 us; speedup vs baseline: 2.2357x; 2.2357x over previous
//
#include <hip/hip_runtime.h>
#include <hip/hip_bf16.h>

#define NSP   20000
#define NSPAT 10000
#define ESS   160000
#define EBIP  320000
#define ESP   320000

static inline int cdiv_host(long a, long b) { return (int)((a + b - 1) / b); }

__device__ __forceinline__ float wave_red_sum(float p) {
#pragma unroll
  for (int m = 32; m >= 1; m >>= 1) p += __shfl_xor(p, m, 64);
  return p;
}

// ---------------------------------------------------------------------------
// mask format detector: 0 = int32 {0,1}, 1 = bytes {0,1}, 2 = float32 {0,1.0f}
// ---------------------------------------------------------------------------
__global__ void detect_mask_kernel(const unsigned int* __restrict__ m, int* __restrict__ flag) {
  if (threadIdx.x == 0 && blockIdx.x == 0) {
    int allint = 1, allfloat = 1;
    for (int i = 0; i < 256; ++i) {
      unsigned int w = m[i];
      if (w != 0u && w != 1u) allint = 0;
      if (w != 0u && w != 0x3f800000u) allfloat = 0;
    }
    *flag = allint ? 0 : (allfloat ? 2 : 1);
  }
}

// ---------------------------------------------------------------------------
// species input concat: [mean(32) | std(32) | vis(32) | gen(64) | phylo(128)]
// ---------------------------------------------------------------------------
__global__ void build_spcat_kernel(const float* __restrict__ mean, const float* __restrict__ stdv,
                                   const void* __restrict__ mask, const int* __restrict__ flag,
                                   const float* __restrict__ gen, const float* __restrict__ phy,
                                   float* __restrict__ out) {
  const long total = (long)NSP * 288;
  int mode = *flag;
  for (long i = (long)blockIdx.x * blockDim.x + threadIdx.x; i < total;
       i += (long)gridDim.x * blockDim.x) {
    int n = (int)(i / 288), c = (int)(i % 288);
    float v;
    if (c < 32) v = mean[(long)n * 32 + c];
    else if (c < 64) v = stdv[(long)n * 32 + (c - 32)];
    else if (c < 96) {
      long j = (long)n * 32 + (c - 64);
      int mv;
      if (mode == 0) mv = ((const int*)mask)[j];
      else if (mode == 2) mv = (((const float*)mask)[j] != 0.0f);
      else mv = (int)((const unsigned char*)mask)[j];
      v = mv ? 0.f : 1.f;   // vis = ~mask
    } else if (c < 160) v = gen[(long)n * 64 + (c - 96)];
    else v = phy[(long)n * 128 + (c - 160)];
    out[i] = v;
  }
}

__global__ void concat2_kernel(const float* __restrict__ A, int wa,
                               const float* __restrict__ B, int wb,
                               int M, float* __restrict__ out) {
  const int wt = wa + wb;
  const long total = (long)M * wt;
  for (long i = (long)blockIdx.x * blockDim.x + threadIdx.x; i < total;
       i += (long)gridDim.x * blockDim.x) {
    int m = (int)(i / wt), c = (int)(i % wt);
    out[i] = (c < wa) ? A[(long)m * wa + c] : B[(long)m * wb + (c - wa)];
  }
}

// ---------------------------------------------------------------------------
// CSR build: count + per-edge rank (+ optional ea sum) in ONE atomic pass,
// then scan, then conflict-free scatter using the saved rank.
// ---------------------------------------------------------------------------
__global__ void count_rank_kernel(const int* __restrict__ col, const float* __restrict__ ea,
                                  int E, int* __restrict__ cnt, int* __restrict__ rank,
                                  float* __restrict__ easum) {
  for (int i = blockIdx.x * blockDim.x + threadIdx.x; i < E; i += gridDim.x * blockDim.x) {
    int d = col[i];
    rank[i] = atomicAdd(&cnt[d], 1);
    if (easum) atomicAdd(&easum[d], ea[i]);
  }
}

__global__ __launch_bounds__(1024) void scan_kernel(const int* __restrict__ cnt, int n,
                                                    int* __restrict__ ptr) {
  __shared__ int part[1024];
  int t = threadIdx.x;
  int ch = (n + 1023) / 1024;
  int beg = t * ch, end = min(beg + ch, n);
  int s = 0;
  for (int i = beg; i < end; ++i) s += cnt[i];
  part[t] = s;
  __syncthreads();
  for (int off = 1; off < 1024; off <<= 1) {
    int v = (t >= off) ? part[t - off] : 0;
    __syncthreads();
    part[t] += v;
    __syncthreads();
  }
  int run = (t == 0) ? 0 : part[t - 1];
  for (int i = beg; i < end; ++i) { ptr[i] = run; run += cnt[i]; }
  if (t == 1023) ptr[n] = part[1023];
}

__global__ void scatter_kernel(const int* __restrict__ row, const int* __restrict__ col,
                               const float* __restrict__ ea, int E,
                               const int* __restrict__ ptr, const int* __restrict__ rank,
                               int* __restrict__ csrc, float* __restrict__ cea) {
  for (int i = blockIdx.x * blockDim.x + threadIdx.x; i < E; i += gridDim.x * blockDim.x) {
    int pos = ptr[col[i]] + rank[i];
    csrc[pos] = row[i];
    cea[pos] = ea[i];
  }
}

__global__ void leafin_kernel(const float* __restrict__ s, const int* __restrict__ cnt, int N,
                              float* __restrict__ lea) {
  for (int i = blockIdx.x * blockDim.x + threadIdx.x; i < N; i += gridDim.x * blockDim.x)
    lea[i] = s[i] / (float)max(cnt[i], 1);
}

// dot_e[h] = sum_c We[h*64+c] * a_e[h*64+c]; all 5 layers in one launch
__global__ void dote_all_kernel(const float* __restrict__ We0, const float* __restrict__ ae0,
                                const float* __restrict__ We1, const float* __restrict__ ae1,
                                const float* __restrict__ Web, const float* __restrict__ aeb,
                                const float* __restrict__ We2, const float* __restrict__ ae2,
                                const float* __restrict__ We3, const float* __restrict__ ae3,
                                float* __restrict__ dotes) {
  int b = blockIdx.x, t = threadIdx.x;
  const float *We, *ae;
  int n, off;
  switch (b) {
    case 0: We = We0; ae = ae0; n = 256; off = 0; break;
    case 1: We = We1; ae = ae1; n = 256; off = 4; break;
    case 2: We = Web; ae = aeb; n = 64;  off = 8; break;
    case 3: We = We2; ae = ae2; n = 256; off = 12; break;
    default: We = We3; ae = ae3; n = 256; off = 16; break;
  }
  if (t < n) {
    float p = wave_red_sum(We[t] * ae[t]);
    if ((t & 63) == 0) dotes[off + (t >> 6)] = p;
  }
}

// ---------------------------------------------------------------------------
// Projection: Y[M,NOUT] = X[M,K] @ W[K,NOUT]  (+bias, +relu), optional per-head
// attention dots al_s/al_d (head = col/64).
// k-group-inner / row-inner interleave -> 8 independent FMA chains;
// float4 X loads; KC*NOUT*4-byte LDS W chunks (32KB for NOUT=256).
// ---------------------------------------------------------------------------
template <int NOUT, int KC>
__global__ __launch_bounds__(256) void proj_kernel(
    const float* __restrict__ X, int M, int K,
    const float* __restrict__ W, const float* __restrict__ bias, int relu,
    const float* __restrict__ a_s, const float* __restrict__ a_d,
    float* __restrict__ al_s, float* __restrict__ al_d,
    float* __restrict__ Y) {
  const int G = 256 / NOUT;          // row groups per block
  const int RPT = 8;                 // rows per thread
  const int H = NOUT / 64;
  __shared__ float wl[KC * NOUT];
  int t = threadIdx.x;
  int col = t % NOUT;
  int rg = t / NOUT;
  long row0 = (long)blockIdx.x * (G * RPT) + (long)rg * RPT;
  long rem = (long)M - row0;
  int rmax = rem >= RPT ? RPT : (rem > 0 ? (int)rem : 0);
  float acc[RPT];
#pragma unroll
  for (int r = 0; r < RPT; ++r) acc[r] = 0.f;

  for (int k0 = 0; k0 < K; k0 += KC) {
    int kc = min(KC, K - k0);        // always a multiple of 4 here
    __syncthreads();
    {
      const float4* wsrc = (const float4*)(W + (long)k0 * NOUT);
      float4* wdst = (float4*)wl;
      for (int i = t; i < (kc * NOUT) >> 2; i += 256) wdst[i] = wsrc[i];
    }
    __syncthreads();
    if (rmax == RPT) {
      for (int k = 0; k < kc; k += 4) {
        float4 xv[RPT];
#pragma unroll
        for (int r = 0; r < RPT; ++r)
          xv[r] = *(const float4*)(X + (row0 + r) * K + k0 + k);
        float w0 = wl[(k + 0) * NOUT + col];
        float w1 = wl[(k + 1) * NOUT + col];
        float w2 = wl[(k + 2) * NOUT + col];
        float w3 = wl[(k + 3) * NOUT + col];
#pragma unroll
        for (int r = 0; r < RPT; ++r) acc[r] = fmaf(xv[r].x, w0, acc[r]);
#pragma unroll
        for (int r = 0; r < RPT; ++r) acc[r] = fmaf(xv[r].y, w1, acc[r]);
#pragma unroll
        for (int r = 0; r < RPT; ++r) acc[r] = fmaf(xv[r].z, w2, acc[r]);
#pragma unroll
        for (int r = 0; r < RPT; ++r) acc[r] = fmaf(xv[r].w, w3, acc[r]);
      }
    } else {
      for (int r = 0; r < rmax; ++r) {
        const float* xr = X + (row0 + r) * K + k0;
        float a = acc[r];
        for (int k = 0; k < kc; ++k) a = fmaf(xr[k], wl[k * NOUT + col], a);
        acc[r] = a;
      }
    }
  }

  float as_c = a_s ? a_s[col] : 0.f;
  float ad_c = a_d ? a_d[col] : 0.f;
  for (int r = 0; r < rmax; ++r) {
    long m = row0 + r;
    float v = acc[r];
    if (bias) v += bias[col];
    if (relu) v = fmaxf(v, 0.f);
    Y[m * NOUT + col] = v;
    if (a_s) {
      float p = wave_red_sum(acc[r] * as_c);
      if ((col & 63) == 0) al_s[m * H + (col >> 6)] = p;
    }
    if (a_d) {
      float p = wave_red_sum(acc[r] * ad_c);
      if ((col & 63) == 0) al_d[m * H + (col >> 6)] = p;
    }
  }
}

// ---------------------------------------------------------------------------
// GAT aggregation: one block per dst node; wave = head, lane = channel.
// Online softmax over incoming edges (+ optional virtual self loop).
// Epilogue: mean over heads (or H=1 passthrough) + bias + relu.
// ---------------------------------------------------------------------------
template <int H, bool SELFLOOP, bool MEANHEADS>
__global__ __launch_bounds__(H * 64) void gat_agg(
    int Nd, const int* __restrict__ dptr, const int* __restrict__ csr_src,
    const float* __restrict__ csr_ea, const float* __restrict__ al_s,
    const float* __restrict__ al_d, const float* __restrict__ dote,
    const float* __restrict__ loop_ea, const float* __restrict__ hs,
    const float* __restrict__ bias, float* __restrict__ out) {
  int n = blockIdx.x;
  if (n >= Nd) return;
  int t = threadIdx.x;
  int h = t >> 6, c = t & 63;
  float m = -INFINITY, den = 0.f, acc = 0.f;
  float ald = al_d[(long)n * H + h];
  float de = dote[h];
  int e0 = dptr[n], e1 = dptr[n + 1];
  for (int e = e0; e < e1; ++e) {
    int src = csr_src[e];
    float l = al_s[(long)src * H + h] + ald + csr_ea[e] * de;
    l = (l > 0.f) ? l : 0.2f * l;
    float hv = hs[(long)src * (H * 64) + (h << 6) + c];
    if (l > m) { float s = expf(m - l); den *= s; acc *= s; m = l; }
    float ex = expf(l - m);
    den += ex;
    acc += ex * hv;
  }
  if (SELFLOOP) {
    float l = al_s[(long)n * H + h] + ald + loop_ea[n] * de;
    l = (l > 0.f) ? l : 0.2f * l;
    float hv = hs[(long)n * (H * 64) + (h << 6) + c];
    if (l > m) { float s = expf(m - l); den *= s; acc *= s; m = l; }
    float ex = expf(l - m);
    den += ex;
    acc += ex * hv;
  }
  float o = acc / (den + 1e-16f);
  if constexpr (MEANHEADS) {
    __shared__ float red[H][64];
    red[h][c] = o;
    __syncthreads();
    if (t < 64) {
      float s = 0.f;
#pragma unroll
      for (int hh = 0; hh < H; ++hh) s += red[hh][t];
      s = s * (1.f / H) + bias[t];
      out[(long)n * 64 + t] = fmaxf(s, 0.f);
    }
  } else {
    out[(long)n * 64 + t] = fmaxf(o + bias[t], 0.f);
  }
}

// ---------------------------------------------------------------------------
// final: mean = ms[:, :32]; std = softplus(ms[:, 32:]) + 1e-6
// ---------------------------------------------------------------------------
__global__ void final_kernel(const float* __restrict__ ms, float* __restrict__ out) {
  const long total = (long)NSP * 32;
  for (long i = (long)blockIdx.x * blockDim.x + threadIdx.x; i < total;
       i += (long)gridDim.x * blockDim.x) {
    long n = i >> 5;
    int c = (int)(i & 31);
    out[i] = ms[n * 64 + c];
    float x = ms[n * 64 + 32 + c];
    float sp = fmaxf(x, 0.f) + log1pf(expf(-fabsf(x)));
    out[total + i] = sp + 1e-6f;
  }
}

// ---------------------------------------------------------------------------
extern "C" void kernel_launch(void* const* d_in, const int* in_sizes, int n_in,
                              void* d_out, int out_size, void* d_ws, size_t ws_size,
                              hipStream_t stream) {
  const float* sp_mean = (const float*)d_in[0];
  const float* sp_std  = (const float*)d_in[1];
  const void*  nanmask = d_in[2];
  const float* sp_gen  = (const float*)d_in[3];
  const float* sp_phy  = (const float*)d_in[4];
  const float* spat_x  = (const float*)d_in[5];
  const float* spat_g  = (const float*)d_in[6];
  const int*   ss_ei   = (const int*)d_in[7];
  const float* ss_ea   = (const float*)d_in[8];
  const int*   bip_ei  = (const int*)d_in[9];
  const float* bip_ea  = (const float*)d_in[10];
  const int*   sp_ei   = (const int*)d_in[11];
  const float* sp_ea   = (const float*)d_in[12];
  const float* sg0_W = (const float*)d_in[13]; const float* sg0_as = (const float*)d_in[14];
  const float* sg0_ad = (const float*)d_in[15]; const float* sg0_ae = (const float*)d_in[16];
  const float* sg0_We = (const float*)d_in[17]; const float* sg0_b = (const float*)d_in[18];
  const float* sg1_W = (const float*)d_in[19]; const float* sg1_as = (const float*)d_in[20];
  const float* sg1_ad = (const float*)d_in[21]; const float* sg1_ae = (const float*)d_in[22];
  const float* sg1_We = (const float*)d_in[23]; const float* sg1_b = (const float*)d_in[24];
  const float* pg0_W = (const float*)d_in[25]; const float* pg0_as = (const float*)d_in[26];
  const float* pg0_ad = (const float*)d_in[27]; const float* pg0_ae = (const float*)d_in[28];
  const float* pg0_We = (const float*)d_in[29]; const float* pg0_b = (const float*)d_in[30];
  const float* pg1_W = (const float*)d_in[31]; const float* pg1_as = (const float*)d_in[32];
  const float* pg1_ad = (const float*)d_in[33]; const float* pg1_ae = (const float*)d_in[34];
  const float* pg1_We = (const float*)d_in[35]; const float* pg1_b = (const float*)d_in[36];
  const float* bp_Ws = (const float*)d_in[37]; const float* bp_Wd = (const float*)d_in[38];
  const float* bp_as = (const float*)d_in[39]; const float* bp_ad = (const float*)d_in[40];
  const float* bp_ae = (const float*)d_in[41]; const float* bp_We = (const float*)d_in[42];
  const float* bp_b  = (const float*)d_in[43];
  const float* sl_W  = (const float*)d_in[44]; const float* sl_b  = (const float*)d_in[45];
  const float* fc_W  = (const float*)d_in[46]; const float* fc_b  = (const float*)d_in[47];

  // ---- workspace layout ----
  char* wsb = (char*)d_ws;
  size_t off = 0;
  auto A = [&](size_t nbytes) -> void* {
    void* p = wsb + off;
    off += (nbytes + 255) & ~(size_t)255;
    return p;
  };
  // --- zeroed region (single memset) ---
  char* zbeg = wsb;
  int*   ss_cnt = (int*)A((NSPAT + 1) * 4);
  int*   bp_cnt = (int*)A((NSP + 1) * 4);
  int*   pp_cnt = (int*)A((NSP + 1) * 4);
  float* ss_sum = (float*)A((size_t)NSPAT * 4);
  float* pp_sum = (float*)A((size_t)NSP * 4);
  size_t zbytes = off;
  // --- rest ---
  int*   flag  = (int*)A(4);
  float* dotes = (float*)A(5 * 4 * sizeof(float));     // 5 layers x <=4 heads
  float* alS   = (float*)A((size_t)NSP * 4 * 4);       // [<=20000, H<=4]
  float* alD   = (float*)A((size_t)NSP * 4 * 4);
  float* R1    = (float*)A((size_t)NSP * 288 * 4);     // sp_cat / part / x_sp
  float* sp_in = (float*)A((size_t)NSP * 64 * 4);
  float* h0    = (float*)A((size_t)NSPAT * 16 * 4);
  float* h_a   = (float*)A((size_t)NSPAT * 64 * 4);
  float* h_b   = (float*)A((size_t)NSPAT * 64 * 4);
  float* HS    = (float*)A((size_t)NSP * 256 * 4);     // projection scratch
  float* sts   = (float*)A((size_t)NSP * 64 * 4);      // bip out, later x2
  float* x1    = (float*)A((size_t)NSP * 64 * 4);      // pg0 out, later ms
  int*   ss_ptr = (int*)A((NSPAT + 1) * 4);
  int*   ss_src = (int*)A((size_t)ESS * 4);
  float* ss_cea = (float*)A((size_t)ESS * 4);
  int*   ss_rnk = (int*)A((size_t)ESS * 4);
  float* ss_lea = (float*)A((size_t)NSPAT * 4);
  int*   bp_ptr = (int*)A((NSP + 1) * 4);
  int*   bp_src = (int*)A((size_t)EBIP * 4);
  float* bp_cea = (float*)A((size_t)EBIP * 4);
  int*   bp_rnk = (int*)A((size_t)EBIP * 4);
  int*   pp_ptr = (int*)A((NSP + 1) * 4);
  int*   pp_src = (int*)A((size_t)ESP * 4);
  float* pp_cea = (float*)A((size_t)ESP * 4);
  int*   pp_rnk = (int*)A((size_t)ESP * 4);
  float* pp_lea = (float*)A((size_t)NSP * 4);
  (void)ws_size; (void)in_sizes; (void)n_in; (void)out_size; (void)zbeg;

  const int TB = 256;
  hipMemsetAsync(wsb, 0, zbytes, stream);

  // ---- graph builds ----
  count_rank_kernel<<<cdiv_host(ESS, TB), TB, 0, stream>>>(ss_ei + ESS, ss_ea, ESS, ss_cnt, ss_rnk, ss_sum);
  scan_kernel<<<1, 1024, 0, stream>>>(ss_cnt, NSPAT, ss_ptr);
  scatter_kernel<<<cdiv_host(ESS, TB), TB, 0, stream>>>(ss_ei, ss_ei + ESS, ss_ea, ESS, ss_ptr, ss_rnk, ss_src, ss_cea);
  leafin_kernel<<<cdiv_host(NSPAT, TB), TB, 0, stream>>>(ss_sum, ss_cnt, NSPAT, ss_lea);

  count_rank_kernel<<<cdiv_host(EBIP, TB), TB, 0, stream>>>(bip_ei + EBIP, bip_ea, EBIP, bp_cnt, bp_rnk, nullptr);
  scan_kernel<<<1, 1024, 0, stream>>>(bp_cnt, NSP, bp_ptr);
  scatter_kernel<<<cdiv_host(EBIP, TB), TB, 0, stream>>>(bip_ei, bip_ei + EBIP, bip_ea, EBIP, bp_ptr, bp_rnk, bp_src, bp_cea);

  count_rank_kernel<<<cdiv_host(ESP, TB), TB, 0, stream>>>(sp_ei + ESP, sp_ea, ESP, pp_cnt, pp_rnk, pp_sum);
  scan_kernel<<<1, 1024, 0, stream>>>(pp_cnt, NSP, pp_ptr);
  scatter_kernel<<<cdiv_host(ESP, TB), TB, 0, stream>>>(sp_ei, sp_ei + ESP, sp_ea, ESP, pp_ptr, pp_rnk, pp_src, pp_cea);
  leafin_kernel<<<cdiv_host(NSP, TB), TB, 0, stream>>>(pp_sum, pp_cnt, NSP, pp_lea);

  dote_all_kernel<<<5, 256, 0, stream>>>(sg0_We, sg0_ae, sg1_We, sg1_ae, bp_We, bp_ae,
                                         pg0_We, pg0_ae, pg1_We, pg1_ae, dotes);

  // ---- species input MLP ----
  detect_mask_kernel<<<1, 64, 0, stream>>>((const unsigned int*)nanmask, flag);
  build_spcat_kernel<<<cdiv_host((long)NSP * 288, TB), TB, 0, stream>>>(sp_mean, sp_std, nanmask, flag, sp_gen, sp_phy, R1);
  proj_kernel<64, 64><<<cdiv_host(NSP, 32), TB, 0, stream>>>(R1, NSP, 288, sl_W, sl_b, 1,
      nullptr, nullptr, nullptr, nullptr, sp_in);

  // ---- spatial GNN ----
  concat2_kernel<<<cdiv_host((long)NSPAT * 16, TB), TB, 0, stream>>>(spat_x, 12, spat_g, 4, NSPAT, h0);
  proj_kernel<256, 32><<<cdiv_host(NSPAT, 8), TB, 0, stream>>>(h0, NSPAT, 16, sg0_W, nullptr, 0,
      sg0_as, sg0_ad, alS, alD, HS);
  gat_agg<4, true, true><<<NSPAT, 256, 0, stream>>>(NSPAT, ss_ptr, ss_src, ss_cea, alS, alD,
      dotes + 0, ss_lea, HS, sg0_b, h_a);
  proj_kernel<256, 32><<<cdiv_host(NSPAT, 8), TB, 0, stream>>>(h_a, NSPAT, 64, sg1_W, nullptr, 0,
      sg1_as, sg1_ad, alS, alD, HS);
  gat_agg<4, true, true><<<NSPAT, 256, 0, stream>>>(NSPAT, ss_ptr, ss_src, ss_cea, alS, alD,
      dotes + 4, ss_lea, HS, sg1_b, h_b);

  // ---- bipartite GAT (spatial -> species), H=1, concat ----
  proj_kernel<64, 64><<<cdiv_host(NSPAT, 32), TB, 0, stream>>>(h_b, NSPAT, 64, bp_Ws, nullptr, 0,
      bp_as, nullptr, alS, nullptr, h_a);   // h_a := hs_src [NSPAT,64]
  concat2_kernel<<<cdiv_host((long)NSP * 192, TB), TB, 0, stream>>>(sp_gen, 64, sp_phy, 128, NSP, R1);
  proj_kernel<64, 64><<<cdiv_host(NSP, 32), TB, 0, stream>>>(R1, NSP, 192, bp_Wd, nullptr, 0,
      nullptr, bp_ad, nullptr, alD, HS);    // HS := hd (only al_d used)
  gat_agg<1, false, false><<<NSP, 64, 0, stream>>>(NSP, bp_ptr, bp_src, bp_cea, alS, alD,
      dotes + 8, nullptr, h_a, bp_b, sts);

  // ---- species GNN ----
  concat2_kernel<<<cdiv_host((long)NSP * 128, TB), TB, 0, stream>>>(sts, 64, sp_in, 64, NSP, R1);
  proj_kernel<256, 32><<<cdiv_host(NSP, 8), TB, 0, stream>>>(R1, NSP, 128, pg0_W, nullptr, 0,
      pg0_as, pg0_ad, alS, alD, HS);
  gat_agg<4, true, true><<<NSP, 256, 0, stream>>>(NSP, pp_ptr, pp_src, pp_cea, alS, alD,
      dotes + 12, pp_lea, HS, pg0_b, x1);
  proj_kernel<256, 32><<<cdiv_host(NSP, 8), TB, 0, stream>>>(x1, NSP, 64, pg1_W, nullptr, 0,
      pg1_as, pg1_ad, alS, alD, HS);
  gat_agg<4, true, true><<<NSP, 256, 0, stream>>>(NSP, pp_ptr, pp_src, pp_cea, alS, alD,
      dotes + 16, pp_lea, HS, pg1_b, sts);  // sts := x2

  // ---- final linear + split ----
  proj_kernel<64, 64><<<cdiv_host(NSP, 32), TB, 0, stream>>>(sts, NSP, 64, fc_W, fc_b, 0,
      nullptr, nullptr, nullptr, nullptr, x1);  // x1 := ms
  final_kernel<<<cdiv_host((long)NSP * 32, TB), TB, 0, stream>>>(x1, (float*)d_out);
}

// Round 3
// 699.723 us; speedup vs baseline: 3.3036x; 1.4776x over previous
//
#include <hip/hip_runtime.h>
#include <hip/hip_bf16.h>

#define NSP   20000
#define NSPAT 10000
#define ESS   160000
#define EBIP  320000
#define ESP   320000

static inline int cdiv_host(long a, long b) { return (int)((a + b - 1) / b); }

__device__ __forceinline__ float wave_red_sum(float p) {
#pragma unroll
  for (int m = 32; m >= 1; m >>= 1) p += __shfl_xor(p, m, 64);
  return p;
}

// ---------------------------------------------------------------------------
// mask format detector: 0 = int32 {0,1}, 1 = bytes {0,1}, 2 = float32 {0,1.0f}
// ---------------------------------------------------------------------------
__global__ void detect_mask_kernel(const unsigned int* __restrict__ m, int* __restrict__ flag) {
  if (threadIdx.x == 0 && blockIdx.x == 0) {
    int allint = 1, allfloat = 1;
    for (int i = 0; i < 256; ++i) {
      unsigned int w = m[i];
      if (w != 0u && w != 1u) allint = 0;
      if (w != 0u && w != 0x3f800000u) allfloat = 0;
    }
    *flag = allint ? 0 : (allfloat ? 2 : 1);
  }
}

// species 96-wide prefix: [mean(32) | std(32) | vis(32)]
__global__ void build_spcat96(const float* __restrict__ mean, const float* __restrict__ stdv,
                              const void* __restrict__ mask, const int* __restrict__ flag,
                              float* __restrict__ out) {
  const long total = (long)NSP * 96;
  int mode = *flag;
  for (long i = (long)blockIdx.x * blockDim.x + threadIdx.x; i < total;
       i += (long)gridDim.x * blockDim.x) {
    int n = (int)(i / 96), c = (int)(i % 96);
    float v;
    if (c < 32) v = mean[(long)n * 32 + c];
    else if (c < 64) v = stdv[(long)n * 32 + (c - 32)];
    else {
      long j = (long)n * 32 + (c - 64);
      int mv;
      if (mode == 0) mv = ((const int*)mask)[j];
      else if (mode == 2) mv = (((const float*)mask)[j] != 0.0f);
      else mv = (int)((const unsigned char*)mask)[j];
      v = mv ? 0.f : 1.f;   // vis = ~mask
    }
    out[i] = v;
  }
}

__global__ void concat2_kernel(const float* __restrict__ A, int wa,
                               const float* __restrict__ B, int wb,
                               int M, float* __restrict__ out) {
  const int wt = wa + wb;
  const long total = (long)M * wt;
  for (long i = (long)blockIdx.x * blockDim.x + threadIdx.x; i < total;
       i += (long)gridDim.x * blockDim.x) {
    int m = (int)(i / wt), c = (int)(i % wt);
    out[i] = (c < wa) ? A[(long)m * wa + c] : B[(long)m * wb + (c - wa)];
  }
}

// ---------------------------------------------------------------------------
// CSR build (3 graphs fused per stage)
// ---------------------------------------------------------------------------
__global__ void count_rank3(
    const int* c1, const float* e1, int E1, int* cnt1, int* rnk1, float* sum1,
    const int* c2, const float* e2, int E2, int* cnt2, int* rnk2, float* sum2,
    const int* c3, const float* e3, int E3, int* cnt3, int* rnk3, float* sum3) {
  int total = E1 + E2 + E3;
  for (int i = blockIdx.x * blockDim.x + threadIdx.x; i < total; i += gridDim.x * blockDim.x) {
    if (i < E1) {
      int d = c1[i]; rnk1[i] = atomicAdd(&cnt1[d], 1); if (sum1) atomicAdd(&sum1[d], e1[i]);
    } else if (i < E1 + E2) {
      int j = i - E1;
      int d = c2[j]; rnk2[j] = atomicAdd(&cnt2[d], 1); if (sum2) atomicAdd(&sum2[d], e2[j]);
    } else {
      int j = i - E1 - E2;
      int d = c3[j]; rnk3[j] = atomicAdd(&cnt3[d], 1); if (sum3) atomicAdd(&sum3[d], e3[j]);
    }
  }
}

__global__ __launch_bounds__(1024) void scan3_kernel(
    const int* cntA, int nA, int* ptrA,
    const int* cntB, int nB, int* ptrB,
    const int* cntC, int nC, int* ptrC) {
  const int* cnt; int n; int* ptr;
  if (blockIdx.x == 0) { cnt = cntA; n = nA; ptr = ptrA; }
  else if (blockIdx.x == 1) { cnt = cntB; n = nB; ptr = ptrB; }
  else { cnt = cntC; n = nC; ptr = ptrC; }
  __shared__ int part[1024];
  int t = threadIdx.x;
  int ch = (n + 1023) / 1024;
  int beg = t * ch, end = min(beg + ch, n);
  int s = 0;
  for (int i = beg; i < end; ++i) s += cnt[i];
  part[t] = s;
  __syncthreads();
  for (int off = 1; off < 1024; off <<= 1) {
    int v = (t >= off) ? part[t - off] : 0;
    __syncthreads();
    part[t] += v;
    __syncthreads();
  }
  int run = (t == 0) ? 0 : part[t - 1];
  for (int i = beg; i < end; ++i) { ptr[i] = run; run += cnt[i]; }
  if (t == 1023) ptr[n] = part[1023];
}

__global__ void scatter3_kernel(
    const int* r1, const int* c1, const float* e1, int E1, const int* p1, const int* k1, int* s1, float* a1,
    const int* r2, const int* c2, const float* e2, int E2, const int* p2, const int* k2, int* s2, float* a2,
    const int* r3, const int* c3, const float* e3, int E3, const int* p3, const int* k3, int* s3, float* a3) {
  int total = E1 + E2 + E3;
  for (int i = blockIdx.x * blockDim.x + threadIdx.x; i < total; i += gridDim.x * blockDim.x) {
    if (i < E1) {
      int pos = p1[c1[i]] + k1[i]; s1[pos] = r1[i]; a1[pos] = e1[i];
    } else if (i < E1 + E2) {
      int j = i - E1;
      int pos = p2[c2[j]] + k2[j]; s2[pos] = r2[j]; a2[pos] = e2[j];
    } else {
      int j = i - E1 - E2;
      int pos = p3[c3[j]] + k3[j]; s3[pos] = r3[j]; a3[pos] = e3[j];
    }
  }
}

__global__ void leafin2_kernel(const float* sA, const int* cA, int nA, float* lA,
                               const float* sB, const int* cB, int nB, float* lB) {
  for (int i = blockIdx.x * blockDim.x + threadIdx.x; i < nA + nB; i += gridDim.x * blockDim.x) {
    if (i < nA) lA[i] = sA[i] / (float)max(cA[i], 1);
    else { int j = i - nA; lB[j] = sB[j] / (float)max(cB[j], 1); }
  }
}

// dot_e[h] = sum_c We[h*64+c] * a_e[h*64+c]; all 5 layers in one launch
__global__ void dote_all_kernel(const float* __restrict__ We0, const float* __restrict__ ae0,
                                const float* __restrict__ We1, const float* __restrict__ ae1,
                                const float* __restrict__ Web, const float* __restrict__ aeb,
                                const float* __restrict__ We2, const float* __restrict__ ae2,
                                const float* __restrict__ We3, const float* __restrict__ ae3,
                                float* __restrict__ dotes) {
  int b = blockIdx.x, t = threadIdx.x;
  const float *We, *ae;
  int n, off;
  switch (b) {
    case 0: We = We0; ae = ae0; n = 256; off = 0; break;
    case 1: We = We1; ae = ae1; n = 256; off = 4; break;
    case 2: We = Web; ae = aeb; n = 64;  off = 8; break;
    case 3: We = We2; ae = ae2; n = 256; off = 12; break;
    default: We = We3; ae = ae3; n = 256; off = 16; break;
  }
  if (t < n) {
    float p = wave_red_sum(We[t] * ae[t]);
    if ((t & 63) == 0) dotes[off + (t >> 6)] = p;
  }
}

// ---------------------------------------------------------------------------
// Projection: Y[M,NOUT] = X @ W (+bias/relu/final-split), X given as up to 5
// row-major segments (widths all multiples of 32 -> each 32-k chunk is in one
// segment).  Per thread: 4 cols x 8 rows.  X and W staged in LDS.
//   NOUT=256: block = 32 rows, X LDS row-major stride 36 (wave-uniform x reads)
//   NOUT=64 : block = 128 rows, X LDS transposed stride 129 (banks spread by 8)
// mode: 0 = bias only, 1 = bias+relu, 2 = final split (mean | softplus+eps)
// ---------------------------------------------------------------------------
struct XSrc { const float* p[5]; int w[5]; int n; };

template <int NOUT>
__global__ __launch_bounds__(256) void proj_kernel(
    XSrc xsrc, int M, int K,
    const float* __restrict__ W, const float* __restrict__ bias, int mode,
    const float* __restrict__ a_s, const float* __restrict__ a_d,
    float* __restrict__ al_s, float* __restrict__ al_d,
    float* __restrict__ Y, float* __restrict__ Y2) {
  constexpr int KC = 32;
  constexpr int RPT = 8;
  constexpr int BR = (NOUT == 256) ? 32 : 128;
  constexpr int KCP = 36;    // padded X stride (row-major variant)
  constexpr int BRP = 129;   // padded X stride (transposed variant)
  constexpr int H = NOUT / 64;
  __shared__ float wl[KC * NOUT];
  __shared__ float xl[(NOUT == 256) ? BR * KCP : KC * BRP];

  int t = threadIdx.x;
  int cg, rg;
  if constexpr (NOUT == 256) { cg = t & 63; rg = t >> 6; }
  else { cg = t & 15; rg = t >> 4; }
  int c0 = cg * 4;
  long row0 = (long)blockIdx.x * BR;

  float acc[RPT][4];
#pragma unroll
  for (int r = 0; r < RPT; ++r)
#pragma unroll
    for (int j = 0; j < 4; ++j) acc[r][j] = 0.f;

  for (int k0 = 0; k0 < K; k0 += KC) {
    int kc = min(KC, K - k0);
    // resolve source segment (uniform)
    int seg = 0; int base = 0;
    while (k0 >= base + xsrc.w[seg]) { base += xsrc.w[seg]; ++seg; }
    const float* Xp = xsrc.p[seg];
    int stride = xsrc.w[seg];
    int kloc = k0 - base;

    __syncthreads();
    // stage W chunk
    {
      const float4* wsrc = (const float4*)(W + (long)k0 * NOUT);
      float4* wdst = (float4*)wl;
      for (int i = t; i < (kc * NOUT) >> 2; i += 256) wdst[i] = wsrc[i];
    }
    // stage X chunk
    for (int i = t; i < BR * 8; i += 256) {
      int r = i >> 3, kq = (i & 7) * 4;
      if (kq < kc) {
        long rr = row0 + r; if (rr >= M) rr = M - 1;
        float4 v = *(const float4*)(Xp + rr * stride + kloc + kq);
        if constexpr (NOUT == 256) {
          *(float4*)(xl + r * KCP + kq) = v;
        } else {
          xl[(kq + 0) * BRP + r] = v.x;
          xl[(kq + 1) * BRP + r] = v.y;
          xl[(kq + 2) * BRP + r] = v.z;
          xl[(kq + 3) * BRP + r] = v.w;
        }
      }
    }
    __syncthreads();

    for (int kg = 0; kg < kc; kg += 4) {
      float4 w0 = *(const float4*)(wl + (kg + 0) * NOUT + c0);
      float4 w1 = *(const float4*)(wl + (kg + 1) * NOUT + c0);
      float4 w2 = *(const float4*)(wl + (kg + 2) * NOUT + c0);
      float4 w3 = *(const float4*)(wl + (kg + 3) * NOUT + c0);
      if constexpr (NOUT == 256) {
        float4 xv[RPT];
#pragma unroll
        for (int r = 0; r < RPT; ++r)
          xv[r] = *(const float4*)(xl + (rg * RPT + r) * KCP + kg);
#pragma unroll
        for (int r = 0; r < RPT; ++r) {
          acc[r][0] = fmaf(xv[r].x, w0.x, acc[r][0]);
          acc[r][1] = fmaf(xv[r].x, w0.y, acc[r][1]);
          acc[r][2] = fmaf(xv[r].x, w0.z, acc[r][2]);
          acc[r][3] = fmaf(xv[r].x, w0.w, acc[r][3]);
          acc[r][0] = fmaf(xv[r].y, w1.x, acc[r][0]);
          acc[r][1] = fmaf(xv[r].y, w1.y, acc[r][1]);
          acc[r][2] = fmaf(xv[r].y, w1.z, acc[r][2]);
          acc[r][3] = fmaf(xv[r].y, w1.w, acc[r][3]);
          acc[r][0] = fmaf(xv[r].z, w2.x, acc[r][0]);
          acc[r][1] = fmaf(xv[r].z, w2.y, acc[r][1]);
          acc[r][2] = fmaf(xv[r].z, w2.z, acc[r][2]);
          acc[r][3] = fmaf(xv[r].z, w2.w, acc[r][3]);
          acc[r][0] = fmaf(xv[r].w, w3.x, acc[r][0]);
          acc[r][1] = fmaf(xv[r].w, w3.y, acc[r][1]);
          acc[r][2] = fmaf(xv[r].w, w3.z, acc[r][2]);
          acc[r][3] = fmaf(xv[r].w, w3.w, acc[r][3]);
        }
      } else {
#pragma unroll
        for (int r = 0; r < RPT; ++r) {
          int rr = rg * RPT + r;
          float x0 = xl[(kg + 0) * BRP + rr];
          float x1 = xl[(kg + 1) * BRP + rr];
          float x2 = xl[(kg + 2) * BRP + rr];
          float x3 = xl[(kg + 3) * BRP + rr];
          acc[r][0] = fmaf(x0, w0.x, acc[r][0]);
          acc[r][1] = fmaf(x0, w0.y, acc[r][1]);
          acc[r][2] = fmaf(x0, w0.z, acc[r][2]);
          acc[r][3] = fmaf(x0, w0.w, acc[r][3]);
          acc[r][0] = fmaf(x1, w1.x, acc[r][0]);
          acc[r][1] = fmaf(x1, w1.y, acc[r][1]);
          acc[r][2] = fmaf(x1, w1.z, acc[r][2]);
          acc[r][3] = fmaf(x1, w1.w, acc[r][3]);
          acc[r][0] = fmaf(x2, w2.x, acc[r][0]);
          acc[r][1] = fmaf(x2, w2.y, acc[r][1]);
          acc[r][2] = fmaf(x2, w2.z, acc[r][2]);
          acc[r][3] = fmaf(x2, w2.w, acc[r][3]);
          acc[r][0] = fmaf(x3, w3.x, acc[r][0]);
          acc[r][1] = fmaf(x3, w3.y, acc[r][1]);
          acc[r][2] = fmaf(x3, w3.z, acc[r][2]);
          acc[r][3] = fmaf(x3, w3.w, acc[r][3]);
        }
      }
    }
  }

  float4 asv = make_float4(0.f, 0.f, 0.f, 0.f);
  float4 adv = make_float4(0.f, 0.f, 0.f, 0.f);
  float4 bv = make_float4(0.f, 0.f, 0.f, 0.f);
  if (a_s) asv = *(const float4*)(a_s + c0);
  if (a_d) adv = *(const float4*)(a_d + c0);
  if (bias) bv = *(const float4*)(bias + c0);

#pragma unroll
  for (int r = 0; r < RPT; ++r) {
    long m = row0 + (long)rg * RPT + r;
    bool ok = m < M;
    float v0 = acc[r][0] + bv.x, v1 = acc[r][1] + bv.y;
    float v2 = acc[r][2] + bv.z, v3 = acc[r][3] + bv.w;
    if (mode == 1) {
      v0 = fmaxf(v0, 0.f); v1 = fmaxf(v1, 0.f);
      v2 = fmaxf(v2, 0.f); v3 = fmaxf(v3, 0.f);
    }
    if (mode == 2) {
      if (ok) {
        if (c0 < 32) {
          *(float4*)(Y + m * 32 + c0) = make_float4(v0, v1, v2, v3);
        } else {
          float4 o;
          o.x = fmaxf(v0, 0.f) + log1pf(__expf(-fabsf(v0))) + 1e-6f;
          o.y = fmaxf(v1, 0.f) + log1pf(__expf(-fabsf(v1))) + 1e-6f;
          o.z = fmaxf(v2, 0.f) + log1pf(__expf(-fabsf(v2))) + 1e-6f;
          o.w = fmaxf(v3, 0.f) + log1pf(__expf(-fabsf(v3))) + 1e-6f;
          *(float4*)(Y2 + m * 32 + (c0 - 32)) = o;
        }
      }
    } else if (ok) {
      *(float4*)(Y + m * NOUT + c0) = make_float4(v0, v1, v2, v3);
    }
    if (a_s) {
      float s = acc[r][0] * asv.x + acc[r][1] * asv.y + acc[r][2] * asv.z + acc[r][3] * asv.w;
      s += __shfl_xor(s, 1); s += __shfl_xor(s, 2);
      s += __shfl_xor(s, 4); s += __shfl_xor(s, 8);
      if (ok && (cg & 15) == 0) al_s[m * H + (c0 >> 6)] = s;
    }
    if (a_d) {
      float s = acc[r][0] * adv.x + acc[r][1] * adv.y + acc[r][2] * adv.z + acc[r][3] * adv.w;
      s += __shfl_xor(s, 1); s += __shfl_xor(s, 2);
      s += __shfl_xor(s, 4); s += __shfl_xor(s, 8);
      if (ok && (cg & 15) == 0) al_d[m * H + (c0 >> 6)] = s;
    }
  }
}

// ---------------------------------------------------------------------------
// GAT aggregation: one block per dst node; wave = head, lane = channel.
// 2 independent online-softmax states for ILP, merged at end.
// ---------------------------------------------------------------------------
__device__ __forceinline__ void gat_upd(float l, float hv, float& m, float& den, float& acc) {
  if (l > m) { float s = __expf(m - l); den *= s; acc *= s; m = l; }
  float ex = __expf(l - m);
  den += ex;
  acc += ex * hv;
}

template <int H, bool SELFLOOP, bool MEANHEADS>
__global__ __launch_bounds__(H * 64) void gat_agg(
    int Nd, const int* __restrict__ dptr, const int* __restrict__ csr_src,
    const float* __restrict__ csr_ea, const float* __restrict__ al_s,
    const float* __restrict__ al_d, const float* __restrict__ dote,
    const float* __restrict__ loop_ea, const float* __restrict__ hs,
    const float* __restrict__ bias, float* __restrict__ out) {
  int n = blockIdx.x;
  if (n >= Nd) return;
  int t = threadIdx.x;
  int h = t >> 6, c = t & 63;
  float ald = al_d[(long)n * H + h];
  float de = dote[h];
  int e0 = dptr[n], e1 = dptr[n + 1];
  float m0 = -INFINITY, d0 = 0.f, a0 = 0.f;
  float m1 = -INFINITY, d1 = 0.f, a1 = 0.f;
  int e = e0;
  for (; e + 2 <= e1; e += 2) {
    int s0 = csr_src[e], s1 = csr_src[e + 1];
    float l0 = al_s[(long)s0 * H + h] + ald + csr_ea[e] * de;
    float l1 = al_s[(long)s1 * H + h] + ald + csr_ea[e + 1] * de;
    l0 = (l0 > 0.f) ? l0 : 0.2f * l0;
    l1 = (l1 > 0.f) ? l1 : 0.2f * l1;
    float hv0 = hs[(long)s0 * (H * 64) + (h << 6) + c];
    float hv1 = hs[(long)s1 * (H * 64) + (h << 6) + c];
    gat_upd(l0, hv0, m0, d0, a0);
    gat_upd(l1, hv1, m1, d1, a1);
  }
  if (e < e1) {
    int s0 = csr_src[e];
    float l0 = al_s[(long)s0 * H + h] + ald + csr_ea[e] * de;
    l0 = (l0 > 0.f) ? l0 : 0.2f * l0;
    float hv0 = hs[(long)s0 * (H * 64) + (h << 6) + c];
    gat_upd(l0, hv0, m0, d0, a0);
  }
  if (m1 != -INFINITY) {
    float M = fmaxf(m0, m1);
    float sA = (m0 == -INFINITY) ? 0.f : __expf(m0 - M);
    float sB = __expf(m1 - M);
    d0 = d0 * sA + d1 * sB;
    a0 = a0 * sA + a1 * sB;
    m0 = M;
  }
  if (SELFLOOP) {
    float l = al_s[(long)n * H + h] + ald + loop_ea[n] * de;
    l = (l > 0.f) ? l : 0.2f * l;
    float hv = hs[(long)n * (H * 64) + (h << 6) + c];
    gat_upd(l, hv, m0, d0, a0);
  }
  float o = a0 / (d0 + 1e-16f);
  if constexpr (MEANHEADS) {
    __shared__ float red[H][64];
    red[h][c] = o;
    __syncthreads();
    if (t < 64) {
      float s = 0.f;
#pragma unroll
      for (int hh = 0; hh < H; ++hh) s += red[hh][t];
      s = s * (1.f / H) + bias[t];
      out[(long)n * 64 + t] = fmaxf(s, 0.f);
    }
  } else {
    out[(long)n * 64 + t] = fmaxf(o + bias[t], 0.f);
  }
}

// ---------------------------------------------------------------------------
extern "C" void kernel_launch(void* const* d_in, const int* in_sizes, int n_in,
                              void* d_out, int out_size, void* d_ws, size_t ws_size,
                              hipStream_t stream) {
  const float* sp_mean = (const float*)d_in[0];
  const float* sp_std  = (const float*)d_in[1];
  const void*  nanmask = d_in[2];
  const float* sp_gen  = (const float*)d_in[3];
  const float* sp_phy  = (const float*)d_in[4];
  const float* spat_x  = (const float*)d_in[5];
  const float* spat_g  = (const float*)d_in[6];
  const int*   ss_ei   = (const int*)d_in[7];
  const float* ss_ea   = (const float*)d_in[8];
  const int*   bip_ei  = (const int*)d_in[9];
  const float* bip_ea  = (const float*)d_in[10];
  const int*   sp_ei   = (const int*)d_in[11];
  const float* sp_ea   = (const float*)d_in[12];
  const float* sg0_W = (const float*)d_in[13]; const float* sg0_as = (const float*)d_in[14];
  const float* sg0_ad = (const float*)d_in[15]; const float* sg0_ae = (const float*)d_in[16];
  const float* sg0_We = (const float*)d_in[17]; const float* sg0_b = (const float*)d_in[18];
  const float* sg1_W = (const float*)d_in[19]; const float* sg1_as = (const float*)d_in[20];
  const float* sg1_ad = (const float*)d_in[21]; const float* sg1_ae = (const float*)d_in[22];
  const float* sg1_We = (const float*)d_in[23]; const float* sg1_b = (const float*)d_in[24];
  const float* pg0_W = (const float*)d_in[25]; const float* pg0_as = (const float*)d_in[26];
  const float* pg0_ad = (const float*)d_in[27]; const float* pg0_ae = (const float*)d_in[28];
  const float* pg0_We = (const float*)d_in[29]; const float* pg0_b = (const float*)d_in[30];
  const float* pg1_W = (const float*)d_in[31]; const float* pg1_as = (const float*)d_in[32];
  const float* pg1_ad = (const float*)d_in[33]; const float* pg1_ae = (const float*)d_in[34];
  const float* pg1_We = (const float*)d_in[35]; const float* pg1_b = (const float*)d_in[36];
  const float* bp_Ws = (const float*)d_in[37]; const float* bp_Wd = (const float*)d_in[38];
  const float* bp_as = (const float*)d_in[39]; const float* bp_ad = (const float*)d_in[40];
  const float* bp_ae = (const float*)d_in[41]; const float* bp_We = (const float*)d_in[42];
  const float* bp_b  = (const float*)d_in[43];
  const float* sl_W  = (const float*)d_in[44]; const float* sl_b  = (const float*)d_in[45];
  const float* fc_W  = (const float*)d_in[46]; const float* fc_b  = (const float*)d_in[47];

  // ---- workspace layout ----
  char* wsb = (char*)d_ws;
  size_t off = 0;
  auto A = [&](size_t nbytes) -> void* {
    void* p = wsb + off;
    off += (nbytes + 255) & ~(size_t)255;
    return p;
  };
  // --- zeroed region (single memset) ---
  int*   ss_cnt = (int*)A((NSPAT + 1) * 4);
  int*   bp_cnt = (int*)A((NSP + 1) * 4);
  int*   pp_cnt = (int*)A((NSP + 1) * 4);
  float* ss_sum = (float*)A((size_t)NSPAT * 4);
  float* pp_sum = (float*)A((size_t)NSP * 4);
  size_t zbytes = off;
  // --- rest ---
  int*   flag  = (int*)A(4);
  float* dotes = (float*)A(5 * 4 * sizeof(float));
  float* alS   = (float*)A((size_t)NSP * 4 * 4);
  float* alD   = (float*)A((size_t)NSP * 4 * 4);
  float* spc96 = (float*)A((size_t)NSP * 96 * 4);
  float* sp_in = (float*)A((size_t)NSP * 64 * 4);
  float* h0    = (float*)A((size_t)NSPAT * 16 * 4);
  float* h_a   = (float*)A((size_t)NSPAT * 64 * 4);
  float* h_b   = (float*)A((size_t)NSPAT * 64 * 4);
  float* HS    = (float*)A((size_t)NSP * 256 * 4);
  float* sts   = (float*)A((size_t)NSP * 64 * 4);
  float* x1    = (float*)A((size_t)NSP * 64 * 4);
  int*   ss_ptr = (int*)A((NSPAT + 1) * 4);
  int*   ss_src = (int*)A((size_t)ESS * 4);
  float* ss_cea = (float*)A((size_t)ESS * 4);
  int*   ss_rnk = (int*)A((size_t)ESS * 4);
  float* ss_lea = (float*)A((size_t)NSPAT * 4);
  int*   bp_ptr = (int*)A((NSP + 1) * 4);
  int*   bp_src = (int*)A((size_t)EBIP * 4);
  float* bp_cea = (float*)A((size_t)EBIP * 4);
  int*   bp_rnk = (int*)A((size_t)EBIP * 4);
  int*   pp_ptr = (int*)A((NSP + 1) * 4);
  int*   pp_src = (int*)A((size_t)ESP * 4);
  float* pp_cea = (float*)A((size_t)ESP * 4);
  int*   pp_rnk = (int*)A((size_t)ESP * 4);
  float* pp_lea = (float*)A((size_t)NSP * 4);
  (void)ws_size; (void)in_sizes; (void)n_in; (void)out_size;

  const int TB = 256;
  hipMemsetAsync(wsb, 0, zbytes, stream);

  // ---- graph builds (fused) ----
  count_rank3<<<cdiv_host(ESS + EBIP + ESP, TB), TB, 0, stream>>>(
      ss_ei + ESS, ss_ea, ESS, ss_cnt, ss_rnk, ss_sum,
      bip_ei + EBIP, bip_ea, EBIP, bp_cnt, bp_rnk, nullptr,
      sp_ei + ESP, sp_ea, ESP, pp_cnt, pp_rnk, pp_sum);
  scan3_kernel<<<3, 1024, 0, stream>>>(ss_cnt, NSPAT, ss_ptr, bp_cnt, NSP, bp_ptr, pp_cnt, NSP, pp_ptr);
  scatter3_kernel<<<cdiv_host(ESS + EBIP + ESP, TB), TB, 0, stream>>>(
      ss_ei, ss_ei + ESS, ss_ea, ESS, ss_ptr, ss_rnk, ss_src, ss_cea,
      bip_ei, bip_ei + EBIP, bip_ea, EBIP, bp_ptr, bp_rnk, bp_src, bp_cea,
      sp_ei, sp_ei + ESP, sp_ea, ESP, pp_ptr, pp_rnk, pp_src, pp_cea);
  leafin2_kernel<<<cdiv_host(NSPAT + NSP, TB), TB, 0, stream>>>(
      ss_sum, ss_cnt, NSPAT, ss_lea, pp_sum, pp_cnt, NSP, pp_lea);

  dote_all_kernel<<<5, 256, 0, stream>>>(sg0_We, sg0_ae, sg1_We, sg1_ae, bp_We, bp_ae,
                                         pg0_We, pg0_ae, pg1_We, pg1_ae, dotes);

  // ---- species input MLP: sp_in = relu([spc96|gen|phy] @ sl_W + sl_b) ----
  detect_mask_kernel<<<1, 64, 0, stream>>>((const unsigned int*)nanmask, flag);
  build_spcat96<<<cdiv_host((long)NSP * 96, TB), TB, 0, stream>>>(sp_mean, sp_std, nanmask, flag, spc96);
  {
    XSrc xs{}; xs.p[0] = spc96; xs.w[0] = 96; xs.p[1] = sp_gen; xs.w[1] = 64;
    xs.p[2] = sp_phy; xs.w[2] = 128; xs.n = 3;
    proj_kernel<64><<<cdiv_host(NSP, 128), TB, 0, stream>>>(xs, NSP, 288, sl_W, sl_b, 1,
        nullptr, nullptr, nullptr, nullptr, sp_in, nullptr);
  }

  // ---- spatial GNN ----
  concat2_kernel<<<cdiv_host((long)NSPAT * 16, TB), TB, 0, stream>>>(spat_x, 12, spat_g, 4, NSPAT, h0);
  {
    XSrc xs{}; xs.p[0] = h0; xs.w[0] = 16; xs.n = 1;
    proj_kernel<256><<<cdiv_host(NSPAT, 32), TB, 0, stream>>>(xs, NSPAT, 16, sg0_W, nullptr, 0,
        sg0_as, sg0_ad, alS, alD, HS, nullptr);
  }
  gat_agg<4, true, true><<<NSPAT, 256, 0, stream>>>(NSPAT, ss_ptr, ss_src, ss_cea, alS, alD,
      dotes + 0, ss_lea, HS, sg0_b, h_a);
  {
    XSrc xs{}; xs.p[0] = h_a; xs.w[0] = 64; xs.n = 1;
    proj_kernel<256><<<cdiv_host(NSPAT, 32), TB, 0, stream>>>(xs, NSPAT, 64, sg1_W, nullptr, 0,
        sg1_as, sg1_ad, alS, alD, HS, nullptr);
  }
  gat_agg<4, true, true><<<NSPAT, 256, 0, stream>>>(NSPAT, ss_ptr, ss_src, ss_cea, alS, alD,
      dotes + 4, ss_lea, HS, sg1_b, h_b);

  // ---- bipartite GAT (spatial -> species), H=1, concat ----
  {
    XSrc xs{}; xs.p[0] = h_b; xs.w[0] = 64; xs.n = 1;
    proj_kernel<64><<<cdiv_host(NSPAT, 128), TB, 0, stream>>>(xs, NSPAT, 64, bp_Ws, nullptr, 0,
        bp_as, nullptr, alS, nullptr, h_a, nullptr);   // h_a := hs_src
  }
  {
    XSrc xs{}; xs.p[0] = sp_gen; xs.w[0] = 64; xs.p[1] = sp_phy; xs.w[1] = 128; xs.n = 2;
    proj_kernel<64><<<cdiv_host(NSP, 128), TB, 0, stream>>>(xs, NSP, 192, bp_Wd, nullptr, 0,
        nullptr, bp_ad, nullptr, alD, HS, nullptr);    // HS := hd (only al_d used)
  }
  gat_agg<1, false, false><<<NSP, 64, 0, stream>>>(NSP, bp_ptr, bp_src, bp_cea, alS, alD,
      dotes + 8, nullptr, h_a, bp_b, sts);

  // ---- species GNN ----
  {
    XSrc xs{}; xs.p[0] = sts; xs.w[0] = 64; xs.p[1] = sp_in; xs.w[1] = 64; xs.n = 2;
    proj_kernel<256><<<cdiv_host(NSP, 32), TB, 0, stream>>>(xs, NSP, 128, pg0_W, nullptr, 0,
        pg0_as, pg0_ad, alS, alD, HS, nullptr);
  }
  gat_agg<4, true, true><<<NSP, 256, 0, stream>>>(NSP, pp_ptr, pp_src, pp_cea, alS, alD,
      dotes + 12, pp_lea, HS, pg0_b, x1);
  {
    XSrc xs{}; xs.p[0] = x1; xs.w[0] = 64; xs.n = 1;
    proj_kernel<256><<<cdiv_host(NSP, 32), TB, 0, stream>>>(xs, NSP, 64, pg1_W, nullptr, 0,
        pg1_as, pg1_ad, alS, alD, HS, nullptr);
  }
  gat_agg<4, true, true><<<NSP, 256, 0, stream>>>(NSP, pp_ptr, pp_src, pp_cea, alS, alD,
      dotes + 16, pp_lea, HS, pg1_b, sts);  // sts := x2

  // ---- final linear fused with split/softplus ----
  {
    XSrc xs{}; xs.p[0] = sts; xs.w[0] = 64; xs.n = 1;
    proj_kernel<64><<<cdiv_host(NSP, 128), TB, 0, stream>>>(xs, NSP, 64, fc_W, fc_b, 2,
        nullptr, nullptr, nullptr, nullptr, (float*)d_out, (float*)d_out + (long)NSP * 32);
  }
}